// Round 1
// baseline (30748.535 us; speedup 1.0000x reference)
//
#include <hip/hip_runtime.h>

#define BB 8
#define TT 2000
#define DD 64
#define NN 2000
#define NWG 250
#define COLS 8
#define THREADS 512
#define CHP 68            // padded chunk stride (64 data + 4 pad floats)
#define RS 2196           // row stride in floats: 32*68 + 20 (bank spread)
#define XS 68

#define LDS_FLOATS (16*RS + 16*XS + 8*16*4)
#define LDS_BYTES  (LDS_FLOATS * 4)

__device__ __forceinline__ float fast_tanh(float v) {
    float e = __expf(2.0f * v);
    return 1.0f - 2.0f / (e + 1.0f);
}

__global__ void __launch_bounds__(THREADS, 1)
esn_recur(const float* __restrict__ x, const float* __restrict__ Win,
          const float* __restrict__ Wres, float* __restrict__ sG,
          float* __restrict__ H, unsigned* __restrict__ slots,
          unsigned* __restrict__ gen)
{
    extern __shared__ float sm[];
    float* wS   = sm;                    // [8][RS]  Wres cols (transposed, chunk-padded)
    float* sS   = sm + 8 * RS;           // [8][RS]  state (chunk-padded)
    float* xS   = sm + 16 * RS;          // [8][XS]
    float* winS = sm + 16 * RS + 8 * XS; // [8][XS]
    float* red  = sm + 16 * RS + 16 * XS;// [8][16][4]

    const int tid  = threadIdx.x;
    const int wg   = blockIdx.x;
    const int col0 = wg * COLS;

    // zero all LDS (zero-pads k=2000..2047 so the padded k-loop adds 0)
    for (int i = tid; i < LDS_FLOATS; i += THREADS) sm[i] = 0.0f;
    __syncthreads();

    // one-time: load Wres slice transposed: wS[c][k] = Wres[k][col0+c]
    {
        const int c = tid & 7;
        for (int k = (tid >> 3); k < NN; k += (THREADS >> 3)) {
            float v = Wres[(size_t)k * NN + col0 + c];
            wS[c * RS + (k >> 6) * CHP + (k & 63)] = v;
        }
    }
    // one-time: Win slice: winS[c][d] = Win[d][col0+c]
    {
        int c = tid >> 6, d = tid & 63;
        winS[c * XS + d] = Win[(size_t)d * NN + col0 + c];
    }

    const int pg = tid & 15;       // pair group: bg(2)|cg(2)
    const int kc = tid >> 4;       // k-chunk 0..31 (64 floats each)
    const int bg = pg >> 2, cg = pg & 3;
    const int b0 = bg * 2, c0 = cg * 2;

    unsigned target = 0;

    for (int t = 0; t < TT; ++t) {
        // stage x_t : xS[b][d]
        {
            int b = tid >> 6, d = tid & 63;
            xS[b * XS + d] = x[((size_t)b * TT + t) * DD + d];
        }
        // stage state into chunk-padded LDS
        if (t > 0) {
            const float4* src = (const float4*)(sG + (size_t)(t & 1) * (BB * NN));
            #pragma unroll
            for (int b = 0; b < BB; ++b) {
                int j = tid;
                if (j < 500) {
                    float4 v = src[b * 500 + j];
                    int k = j * 4;
                    *(float4*)&sS[b * RS + (k >> 6) * CHP + (k & 63)] = v;
                }
            }
        }
        __syncthreads();

        float a00 = 0.f, a01 = 0.f, a10 = 0.f, a11 = 0.f;
        if (t > 0) {
            const float4* sA = (const float4*)&sS[(b0    ) * RS + kc * CHP];
            const float4* sB = (const float4*)&sS[(b0 + 1) * RS + kc * CHP];
            const float4* wA = (const float4*)&wS[(c0    ) * RS + kc * CHP];
            const float4* wB = (const float4*)&wS[(c0 + 1) * RS + kc * CHP];
            #pragma unroll 4
            for (int i = 0; i < 16; ++i) {
                float4 s0 = sA[i], s1 = sB[i], w0 = wA[i], w1 = wB[i];
                a00 = fmaf(s0.x, w0.x, a00); a00 = fmaf(s0.y, w0.y, a00);
                a00 = fmaf(s0.z, w0.z, a00); a00 = fmaf(s0.w, w0.w, a00);
                a01 = fmaf(s0.x, w1.x, a01); a01 = fmaf(s0.y, w1.y, a01);
                a01 = fmaf(s0.z, w1.z, a01); a01 = fmaf(s0.w, w1.w, a01);
                a10 = fmaf(s1.x, w0.x, a10); a10 = fmaf(s1.y, w0.y, a10);
                a10 = fmaf(s1.z, w0.z, a10); a10 = fmaf(s1.w, w0.w, a10);
                a11 = fmaf(s1.x, w1.x, a11); a11 = fmaf(s1.y, w1.y, a11);
                a11 = fmaf(s1.z, w1.z, a11); a11 = fmaf(s1.w, w1.w, a11);
            }
        }
        // reduce over kc quads within each wave (lanes tid^16, tid^32 hold kc^1, kc^2)
        a00 += __shfl_xor(a00, 16); a00 += __shfl_xor(a00, 32);
        a01 += __shfl_xor(a01, 16); a01 += __shfl_xor(a01, 32);
        a10 += __shfl_xor(a10, 16); a10 += __shfl_xor(a10, 32);
        a11 += __shfl_xor(a11, 16); a11 += __shfl_xor(a11, 32);
        if ((tid & 63) < 16) {
            int w = tid >> 6;
            *(float4*)&red[(w * 16 + pg) * 4] = make_float4(a00, a01, a10, a11);
        }
        __syncthreads();

        if (tid < 64) {
            int b = tid >> 3, c = tid & 7;
            int pgq = (b >> 1) * 4 + (c >> 1);
            int ai  = (b & 1) * 2 + (c & 1);
            float acc = 0.f;
            #pragma unroll
            for (int w = 0; w < 8; ++w) acc += red[(w * 16 + pgq) * 4 + ai];
            const float4* xv = (const float4*)&xS[b * XS];
            const float4* wv = (const float4*)&winS[c * XS];
            #pragma unroll
            for (int d4 = 0; d4 < 16; ++d4) {
                float4 xx = xv[d4], ww = wv[d4];
                acc = fmaf(xx.x, ww.x, acc); acc = fmaf(xx.y, ww.y, acc);
                acc = fmaf(xx.z, ww.z, acc); acc = fmaf(xx.w, ww.w, acc);
            }
            float s = fast_tanh(acc);
            sG[(size_t)((t + 1) & 1) * (BB * NN) + b * NN + col0 + c] = s;
            float h = (c & 1) ? s : s * s;                 // even global col -> square
            H[((size_t)t * BB + b) * NN + col0 + c] = h;
        }

        // ---- grid barrier (skip after last step) ----
        if (t < TT - 1) {
            ++target;
            __syncthreads();
            if (wg == 0) {
                if (tid == 0) {
                    __threadfence();
                    __hip_atomic_store(&slots[0], target, __ATOMIC_RELAXED, __HIP_MEMORY_SCOPE_AGENT);
                }
                bool ok;
                do {
                    unsigned v = (tid < NWG)
                        ? __hip_atomic_load(&slots[tid], __ATOMIC_RELAXED, __HIP_MEMORY_SCOPE_AGENT)
                        : target;
                    ok = __syncthreads_and(v >= target) != 0;
                    if (!ok) __builtin_amdgcn_s_sleep(1);
                } while (!ok);
                if (tid == 0) {
                    __hip_atomic_store(gen, target, __ATOMIC_RELAXED, __HIP_MEMORY_SCOPE_AGENT);
                }
            } else {
                if (tid == 0) {
                    __threadfence();
                    __hip_atomic_store(&slots[wg], target, __ATOMIC_RELAXED, __HIP_MEMORY_SCOPE_AGENT);
                    while (__hip_atomic_load(gen, __ATOMIC_RELAXED, __HIP_MEMORY_SCOPE_AGENT) < target)
                        __builtin_amdgcn_s_sleep(1);
                }
            }
            if (tid == 0) __threadfence();   // acquire: invalidate L1/L2 before next staging reads
            __syncthreads();
        }
    }
}

// out[b,t,:] = H[t,b,:] @ Wout   (augmentation already applied in H)
__global__ void __launch_bounds__(256, 1)
esn_out(const float* __restrict__ H, const float* __restrict__ Wout,
        float* __restrict__ out)
{
    __shared__ float Hs[64 * 84];
    __shared__ float Ws[80 * 64];
    const int tid = threadIdx.x;
    const int r0  = blockIdx.x * 64;      // global row = t*8 + b
    const int tr  = tid >> 4;             // 0..15
    const int tc  = tid & 15;             // 0..15
    float acc[4][4] = {{0.f}};

    for (int k0 = 0; k0 < NN; k0 += 80) {
        __syncthreads();
        #pragma unroll
        for (int j = 0; j < 5; ++j) {
            int idx = j * 256 + tid;               // 0..1279
            int r = idx / 20, q = idx % 20;
            float4 v = *(const float4*)&H[(size_t)(r0 + r) * NN + k0 + q * 4];
            *(float4*)&Hs[r * 84 + q * 4] = v;
        }
        #pragma unroll
        for (int j = 0; j < 5; ++j) {
            int idx = j * 256 + tid;
            int kk = idx >> 4, c4 = idx & 15;
            float4 v = *(const float4*)&Wout[(size_t)(k0 + kk) * DD + c4 * 4];
            *(float4*)&Ws[kk * 64 + c4 * 4] = v;
        }
        __syncthreads();
        for (int kk = 0; kk < 80; ++kk) {
            float4 wv = *(const float4*)&Ws[kk * 64 + tc * 4];
            #pragma unroll
            for (int i = 0; i < 4; ++i) {
                float hv = Hs[(tr + 16 * i) * 84 + kk];
                acc[i][0] = fmaf(hv, wv.x, acc[i][0]);
                acc[i][1] = fmaf(hv, wv.y, acc[i][1]);
                acc[i][2] = fmaf(hv, wv.z, acc[i][2]);
                acc[i][3] = fmaf(hv, wv.w, acc[i][3]);
            }
        }
    }
    #pragma unroll
    for (int i = 0; i < 4; ++i) {
        int rg = r0 + tr + 16 * i;
        int t = rg >> 3, b = rg & 7;
        *(float4*)&out[((size_t)b * TT + t) * DD + tc * 4] =
            make_float4(acc[i][0], acc[i][1], acc[i][2], acc[i][3]);
    }
}

extern "C" void kernel_launch(void* const* d_in, const int* in_sizes, int n_in,
                              void* d_out, int out_size, void* d_ws, size_t ws_size,
                              hipStream_t stream)
{
    const float* x    = (const float*)d_in[0];
    const float* Win  = (const float*)d_in[1];
    const float* Wres = (const float*)d_in[2];
    const float* Wout = (const float*)d_in[3];
    float* out = (float*)d_out;

    char* ws = (char*)d_ws;
    unsigned* slots = (unsigned*)ws;                 // 256 uints
    unsigned* gen   = (unsigned*)(ws + 2048);
    float* sG = (float*)(ws + 4096);                 // 2 * 8 * 2000 f32 = 128 KB
    float* H  = (float*)(ws + 4096 + 131072);        // 2000*8*2000 f32 = 128 MB

    hipMemsetAsync(d_ws, 0, 4096, stream);

    hipFuncSetAttribute((const void*)esn_recur,
                        hipFuncAttributeMaxDynamicSharedMemorySize, LDS_BYTES);
    esn_recur<<<NWG, THREADS, LDS_BYTES, stream>>>(x, Win, Wres, sG, H, slots, gen);
    esn_out<<<NWG, 256, 0, stream>>>(H, Wout, out);
}

// Round 2
// 20932.304 us; speedup vs baseline: 1.4690x; 1.4690x over previous
//
#include <hip/hip_runtime.h>

#define BB 8
#define TT 2000
#define DD 64
#define NN 2000
#define NWG 125
#define COLS 16
#define THREADS 512
#define WS_STRIDE 2056     // bf16 row stride (2048 data + 8 pad) -> 4112 B, 4-bank rotate
#define XST 68

// LDS carve (bytes):
//   wS   : 16 * 2056 * 2 = 65792   (Wres^T slice, bf16, K padded+zeroed to 2048)
//   sS   :  8 * 2056 * 2 = 32896   (state, bf16)
//   winS : 16 * 68 * 4   = 4352
//   xS   :  8 * 68 * 4   = 2176
//   red  :  8*8*16 * 4   = 4096
#define LDS_BYTES 109312

typedef __bf16 bf16x8 __attribute__((ext_vector_type(8)));
typedef float f32x4 __attribute__((ext_vector_type(4)));

__device__ __forceinline__ float fast_tanh(float v) {
    float e = __expf(2.0f * v);
    return 1.0f - 2.0f / (e + 1.0f);
}

__global__ void __launch_bounds__(THREADS, 1)
esn_recur(const float* __restrict__ x, const float* __restrict__ Win,
          const float* __restrict__ Wres, __bf16* __restrict__ sG,
          float* __restrict__ H, unsigned* __restrict__ flags)
{
    extern __shared__ char smraw[];
    __bf16* wS   = (__bf16*)smraw;                 // [16][2056]
    __bf16* sS   = wS + 16 * WS_STRIDE;            // [8][2056]
    float*  winS = (float*)(sS + 8 * WS_STRIDE);   // [16][68]
    float*  xS   = winS + 16 * XST;                // [8][68]
    float*  red  = xS + 8 * XST;                   // [8 waves][8 rows][16 cols]

    const int tid  = threadIdx.x;
    const int wg   = blockIdx.x;
    const int col0 = wg * COLS;

    // zero all LDS once (zeroes the K-pad 2000..2047 so padded MFMA adds 0)
    for (int i = tid; i < LDS_BYTES / 4; i += THREADS) ((unsigned*)smraw)[i] = 0u;
    __syncthreads();

    // one-time: Wres slice transposed to bf16: wS[c][k] = Wres[k][col0+c]
    {
        const int c = tid & 15;
        for (int k = tid >> 4; k < NN; k += (THREADS >> 4))
            wS[c * WS_STRIDE + k] = (__bf16)Wres[(size_t)k * NN + col0 + c];
    }
    // one-time: Win slice (f32): winS[c][d] = Win[d][col0+c]
    for (int i = tid; i < COLS * DD; i += THREADS) {
        int c = i >> 6, d = i & 63;
        winS[c * XST + d] = Win[(size_t)d * NN + col0 + c];
    }
    __syncthreads();

    const int wave = tid >> 6;
    const int lane = tid & 63;
    const int arow = (lane & 15) & 7;   // rows 8..15 duplicate 0..7 (C rows 8..15 unused)
    const int bcol = lane & 15;
    const int kgrp = (lane >> 4) * 8;

    for (int t = 0; t < TT; ++t) {
        // stage x_t : xS[b][d]
        {
            int b = tid >> 6, d = tid & 63;
            xS[b * XST + d] = x[((size_t)b * TT + t) * DD + d];
        }
        // stage full state (bf16, 32 KB) into LDS
        if (t > 0) {
            const __bf16* sPrev = sG + (size_t)(t & 1) * (BB * NN);
            const int b = wave;  // 8 waves <-> 8 batch rows
            const uint4* srcRow = (const uint4*)(sPrev + b * NN);
            uint4* dstRow = (uint4*)(sS + b * WS_STRIDE);
            for (int q = lane; q < 250; q += 64) dstRow[q] = srcRow[q];
        }
        __syncthreads();

        // state @ Wres slice via MFMA: wave w handles K slice [w*256, w*256+256)
        f32x4 acc = {0.f, 0.f, 0.f, 0.f};
        if (t > 0) {
            const int kbase = wave * 256 + kgrp;
            #pragma unroll
            for (int m = 0; m < 8; ++m) {
                const int k = kbase + m * 32;
                bf16x8 a = *(const bf16x8*)(sS + arow * WS_STRIDE + k);
                bf16x8 b = *(const bf16x8*)(wS + bcol * WS_STRIDE + k);
                acc = __builtin_amdgcn_mfma_f32_16x16x32_bf16(a, b, acc, 0, 0, 0);
            }
        }
        // write K-partials: lanes 0..31 hold rows 0..7 (row = (lane>>4)*4 + reg)
        if (lane < 32) {
            const int r0 = (lane >> 4) * 4;
            #pragma unroll
            for (int i = 0; i < 4; ++i)
                red[(wave * 8 + r0 + i) * 16 + bcol] = acc[i];
        }
        __syncthreads();

        // finish: sum 8 K-partials + x@Win + tanh; 128 threads = 8b x 16c
        if (tid < BB * COLS) {
            const int b = tid >> 4, c = tid & 15;
            float a2 = 0.f;
            #pragma unroll
            for (int w = 0; w < 8; ++w) a2 += red[(w * 8 + b) * 16 + c];
            const float4* xv = (const float4*)&xS[b * XST];
            const float4* wv = (const float4*)&winS[c * XST];
            #pragma unroll
            for (int d4 = 0; d4 < 16; ++d4) {
                float4 xx = xv[d4], ww = wv[d4];
                a2 = fmaf(xx.x, ww.x, a2); a2 = fmaf(xx.y, ww.y, a2);
                a2 = fmaf(xx.z, ww.z, a2); a2 = fmaf(xx.w, ww.w, a2);
            }
            float s = fast_tanh(a2);
            sG[(size_t)((t + 1) & 1) * (BB * NN) + b * NN + col0 + c] = (__bf16)s;
            float h = (c & 1) ? s : s * s;   // even global col (col0+c, col0 mult of 16)
            H[((size_t)t * BB + b) * NN + col0 + c] = h;
        }

        // ---- all-poll grid barrier (skip after last step) ----
        if (t < TT - 1) {
            const unsigned target = (unsigned)(t + 1);
            __syncthreads();                       // drains vmcnt: stores reached L2
            if (tid == 0) {
                __threadfence();                   // release: wbl2 -> L3
                __hip_atomic_store(&flags[wg], target, __ATOMIC_RELAXED, __HIP_MEMORY_SCOPE_AGENT);
            }
            if (tid < NWG) {
                while (__hip_atomic_load(&flags[tid], __ATOMIC_RELAXED, __HIP_MEMORY_SCOPE_AGENT) < target) {}
            }
            __syncthreads();
            if (tid == 0) __threadfence();         // acquire: invalidate stale L2
            __syncthreads();
        }
    }
}

// out[b,t,:] = H[t,b,:] @ Wout  (augmentation already applied in H)
__global__ void __launch_bounds__(256, 1)
esn_out(const float* __restrict__ H, const float* __restrict__ Wout,
        float* __restrict__ out)
{
    __shared__ float Hs[32 * 84];
    __shared__ float Ws[80 * 64];
    const int tid = threadIdx.x;
    const int r0  = blockIdx.x * 32;      // global row = t*8 + b
    const int tr  = tid >> 4;             // 0..15
    const int tc  = tid & 15;             // 0..15
    float acc[2][4] = {{0.f}};

    for (int k0 = 0; k0 < NN; k0 += 80) {
        __syncthreads();
        for (int idx = tid; idx < 32 * 20; idx += 256) {
            int r = idx / 20, q = idx % 20;
            *(float4*)&Hs[r * 84 + q * 4] =
                *(const float4*)&H[(size_t)(r0 + r) * NN + k0 + q * 4];
        }
        for (int idx = tid; idx < 80 * 16; idx += 256) {
            int kk = idx >> 4, c4 = idx & 15;
            *(float4*)&Ws[kk * 64 + c4 * 4] =
                *(const float4*)&Wout[(size_t)(k0 + kk) * DD + c4 * 4];
        }
        __syncthreads();
        for (int kk = 0; kk < 80; ++kk) {
            float4 wv = *(const float4*)&Ws[kk * 64 + tc * 4];
            #pragma unroll
            for (int i = 0; i < 2; ++i) {
                float hv = Hs[(tr + 16 * i) * 84 + kk];
                acc[i][0] = fmaf(hv, wv.x, acc[i][0]);
                acc[i][1] = fmaf(hv, wv.y, acc[i][1]);
                acc[i][2] = fmaf(hv, wv.z, acc[i][2]);
                acc[i][3] = fmaf(hv, wv.w, acc[i][3]);
            }
        }
    }
    #pragma unroll
    for (int i = 0; i < 2; ++i) {
        int rg = r0 + tr + 16 * i;
        int t = rg >> 3, b = rg & 7;
        *(float4*)&out[((size_t)b * TT + t) * DD + tc * 4] =
            make_float4(acc[i][0], acc[i][1], acc[i][2], acc[i][3]);
    }
}

extern "C" void kernel_launch(void* const* d_in, const int* in_sizes, int n_in,
                              void* d_out, int out_size, void* d_ws, size_t ws_size,
                              hipStream_t stream)
{
    const float* x    = (const float*)d_in[0];
    const float* Win  = (const float*)d_in[1];
    const float* Wres = (const float*)d_in[2];
    const float* Wout = (const float*)d_in[3];
    float* out = (float*)d_out;

    char* ws = (char*)d_ws;
    unsigned* flags = (unsigned*)ws;                 // 125 uints (4 KB reserved)
    __bf16* sG = (__bf16*)(ws + 4096);               // 2 * 8 * 2000 bf16 = 64 KB
    float* H   = (float*)(ws + 4096 + 65536);        // 2000*8*2000 f32 = 128 MB

    hipMemsetAsync(d_ws, 0, 4096, stream);

    hipFuncSetAttribute((const void*)esn_recur,
                        hipFuncAttributeMaxDynamicSharedMemorySize, LDS_BYTES);
    esn_recur<<<NWG, THREADS, LDS_BYTES, stream>>>(x, Win, Wres, sG, H, flags);
    esn_out<<<500, 256, 0, stream>>>(H, Wout, out);
}

// Round 4
// 11453.784 us; speedup vs baseline: 2.6846x; 1.8275x over previous
//
#include <hip/hip_runtime.h>

#define BB 8
#define TT 2000
#define DD 64
#define NN 2000
#define NWG 125
#define COLS 16
#define THREADS 512
#define SROW 2048          // bf16 elements per LDS row (4096 B, swizzled)
#define XST 68

// LDS: wS 16*2048*2=65536, sS 8*2048*2=32768, winS 16*68*4=4352,
//      xS 8*68*4=2176, red 8*8*16*4=4096  -> 108928 B
#define LDS_BYTES (65536 + 32768 + 4352 + 2176 + 4096)

typedef __bf16 bf16x8 __attribute__((ext_vector_type(8)));
typedef float f32x4 __attribute__((ext_vector_type(4)));

__device__ __forceinline__ float fast_tanh(float v) {
    float e = __expf(2.0f * v);
    return 1.0f - 2.0f / (e + 1.0f);
}

// ---- uncached (coherence-point) accessors: sc0 sc1 = bypass L1/L2, served by IC ----
__device__ __forceinline__ uint4 ld_uc4(const uint4* p) {
    uint4 v;
    asm volatile("global_load_dwordx4 %0, %1, off sc0 sc1" : "=v"(v) : "v"(p) : "memory");
    return v;
}
__device__ __forceinline__ void st_uc_u16(void* p, unsigned v) {
    asm volatile("global_store_short %0, %1, off sc0 sc1" :: "v"(p), "v"(v) : "memory");
}
__device__ __forceinline__ void st_uc_u32(void* p, unsigned v) {
    asm volatile("global_store_dword %0, %1, off sc0 sc1" :: "v"(p), "v"(v) : "memory");
}
__device__ __forceinline__ unsigned ld_uc_u32(const void* p) {
    unsigned v;
    asm volatile("global_load_dword %0, %1, off sc0 sc1\n\ts_waitcnt vmcnt(0)"
                 : "=v"(v) : "v"(p) : "memory");
    return v;
}

__global__ void __launch_bounds__(THREADS, 1)
esn_recur(const float* __restrict__ x, const float* __restrict__ Win,
          const float* __restrict__ Wres, __bf16* __restrict__ sG,
          float* __restrict__ H, unsigned* __restrict__ flags)
{
    extern __shared__ char smraw[];
    __bf16* wS   = (__bf16*)smraw;                 // [16][2048] swizzled: blk^(c&7)
    __bf16* sS   = wS + 16 * SROW;                 // [8][2048]  swizzled: blk^row
    float*  winS = (float*)(sS + 8 * SROW);        // [16][68]
    float*  xS   = winS + 16 * XST;                // [8][68]
    float*  red  = xS + 8 * XST;                   // [8 waves][8 rows][16 cols]

    const int tid  = threadIdx.x;
    const int wg   = blockIdx.x;
    const int col0 = wg * COLS;
    const int wave = tid >> 6;
    const int lane = tid & 63;

    // zero all LDS (zeroes K-pad 2000..2047; swizzle maps pad blks to never-written slots)
    for (int i = tid; i < LDS_BYTES / 4; i += THREADS) ((unsigned*)smraw)[i] = 0u;
    __syncthreads();

    // one-time: Wres slice transposed, bf16, XOR-swizzled 16B blocks
    {
        const int c = tid & 15, h = c & 7;
        for (int k = tid >> 4; k < NN; k += 32)
            wS[c * SROW + ((((k >> 3) ^ h) << 3) | (k & 7))] =
                (__bf16)Wres[(size_t)k * NN + col0 + c];
    }
    // one-time: Win slice (f32)
    for (int i = tid; i < COLS * DD; i += THREADS) {
        int c = i >> 6, d = i & 63;
        winS[c * XST + d] = Win[(size_t)d * NN + col0 + c];
    }
    __syncthreads();

    const int arow = lane & 7;        // A-fragment row ((lane&15)&7: rows 8..15 dup 0..7)
    const int quad = lane >> 4;       // k sub-group
    const int bcol = lane & 15;
    const int hb   = bcol & 7;

    for (int t = 0; t < TT; ++t) {
        // stage x_t (cached — read-only, stays in L2)
        {
            int b = tid >> 6, d = tid & 63;
            xS[b * XST + d] = x[((size_t)b * TT + t) * DD + d];
        }
        // stage full state from IC (uncached), wave w <-> batch row w; 250 uint4/row
        if (t > 0) {
            const uint4* srcRow =
                (const uint4*)(sG + (size_t)(t & 1) * (BB * NN) + wave * NN);
            uint4 v0, v1, v2, v3 = make_uint4(0u, 0u, 0u, 0u);
            v0 = ld_uc4(srcRow + lane);
            v1 = ld_uc4(srcRow + lane + 64);
            v2 = ld_uc4(srcRow + lane + 128);
            const bool has4 = (lane < 58);            // 192+lane < 250
            if (has4) v3 = ld_uc4(srcRow + lane + 192);
            // volatile asms stay ordered; "memory" clobber keeps the LDS
            // stores below from hoisting above this wait.
            asm volatile("s_waitcnt vmcnt(0)" ::: "memory");
            __bf16* dst = sS + wave * SROW;
            const int h = wave;                       // wave < 8
            *(uint4*)(dst + (size_t)((lane      ) ^ h) * 8) = v0;
            *(uint4*)(dst + (size_t)((lane +  64) ^ h) * 8) = v1;
            *(uint4*)(dst + (size_t)((lane + 128) ^ h) * 8) = v2;
            if (has4) *(uint4*)(dst + (size_t)((lane + 192) ^ h) * 8) = v3;
        }
        __syncthreads();

        // state @ Wres slice via MFMA: wave w owns K slice [w*256, (w+1)*256)
        f32x4 acc = {0.f, 0.f, 0.f, 0.f};
        if (t > 0) {
            const __bf16* aBase = sS + arow * SROW;
            const __bf16* bBase = wS + bcol * SROW;
            const int blk0 = wave * 32 + quad;
            #pragma unroll
            for (int m = 0; m < 8; ++m) {
                const int blk = blk0 + m * 4;
                bf16x8 a = *(const bf16x8*)(aBase + ((blk ^ arow) << 3));
                bf16x8 b = *(const bf16x8*)(bBase + ((blk ^ hb) << 3));
                acc = __builtin_amdgcn_mfma_f32_16x16x32_bf16(a, b, acc, 0, 0, 0);
            }
        }
        if (lane < 32) {
            const int r0 = (lane >> 4) * 4;
            #pragma unroll
            for (int i = 0; i < 4; ++i)
                red[(wave * 8 + r0 + i) * 16 + bcol] = acc[i];
        }
        __syncthreads();

        // finish: sum K-partials + x@Win + tanh; publish state uncached
        if (tid < BB * COLS) {
            const int b = tid >> 4, c = tid & 15;
            float a2 = 0.f;
            #pragma unroll
            for (int w = 0; w < 8; ++w) a2 += red[(w * 8 + b) * 16 + c];
            const float4* xv = (const float4*)&xS[b * XST];
            const float4* wv = (const float4*)&winS[c * XST];
            #pragma unroll
            for (int d4 = 0; d4 < 16; ++d4) {
                float4 xx = xv[d4], ww = wv[d4];
                a2 = fmaf(xx.x, ww.x, a2); a2 = fmaf(xx.y, ww.y, a2);
                a2 = fmaf(xx.z, ww.z, a2); a2 = fmaf(xx.w, ww.w, a2);
            }
            float s = fast_tanh(a2);
            __bf16 sb = (__bf16)s;
            unsigned short us;
            __builtin_memcpy(&us, &sb, 2);
            st_uc_u16(sG + (size_t)((t + 1) & 1) * (BB * NN) + b * NN + col0 + c,
                      (unsigned)us);
            float hval = (c & 1) ? s : s * s;     // even global col -> square
            H[((size_t)t * BB + b) * NN + col0 + c] = hval;
            asm volatile("s_waitcnt vmcnt(0)" ::: "memory");  // state at IC before barrier
        }

        // ---- all-poll grid barrier, no cache-maintenance ops ----
        if (t < TT - 1) {
            const unsigned target = (unsigned)(t + 1);
            __syncthreads();                        // all waves drained (vmcnt 0)
            if (tid == 0) st_uc_u32(flags + wg, target);
            if (tid < NWG) {
                while (ld_uc_u32(flags + tid) < target) {}
            }
            __syncthreads();
        }
    }
}

// out[b,t,:] = H[t,b,:] @ Wout  (augmentation already applied in H)
__global__ void __launch_bounds__(256, 1)
esn_out(const float* __restrict__ H, const float* __restrict__ Wout,
        float* __restrict__ out)
{
    __shared__ float Hs[64 * 84];
    __shared__ float Ws[80 * 64];
    const int tid = threadIdx.x;
    const int r0  = blockIdx.x * 64;      // global row = t*8 + b
    const int tr  = tid >> 4;             // 0..15
    const int tc  = tid & 15;             // 0..15
    float acc[4][4] = {{0.f}};

    for (int k0 = 0; k0 < NN; k0 += 80) {
        __syncthreads();
        #pragma unroll
        for (int j = 0; j < 5; ++j) {
            int idx = j * 256 + tid;               // 0..1279
            int r = idx / 20, q = idx % 20;
            *(float4*)&Hs[r * 84 + q * 4] =
                *(const float4*)&H[(size_t)(r0 + r) * NN + k0 + q * 4];
        }
        #pragma unroll
        for (int j = 0; j < 5; ++j) {
            int idx = j * 256 + tid;
            int kk = idx >> 4, c4 = idx & 15;
            *(float4*)&Ws[kk * 64 + c4 * 4] =
                *(const float4*)&Wout[(size_t)(k0 + kk) * DD + c4 * 4];
        }
        __syncthreads();
        for (int kk = 0; kk < 80; ++kk) {
            float4 wv = *(const float4*)&Ws[kk * 64 + tc * 4];
            #pragma unroll
            for (int i = 0; i < 4; ++i) {
                float hv = Hs[(tr + 16 * i) * 84 + kk];
                acc[i][0] = fmaf(hv, wv.x, acc[i][0]);
                acc[i][1] = fmaf(hv, wv.y, acc[i][1]);
                acc[i][2] = fmaf(hv, wv.z, acc[i][2]);
                acc[i][3] = fmaf(hv, wv.w, acc[i][3]);
            }
        }
    }
    #pragma unroll
    for (int i = 0; i < 4; ++i) {
        int rg = r0 + tr + 16 * i;
        int t = rg >> 3, b = rg & 7;
        *(float4*)&out[((size_t)b * TT + t) * DD + tc * 4] =
            make_float4(acc[i][0], acc[i][1], acc[i][2], acc[i][3]);
    }
}

extern "C" void kernel_launch(void* const* d_in, const int* in_sizes, int n_in,
                              void* d_out, int out_size, void* d_ws, size_t ws_size,
                              hipStream_t stream)
{
    const float* x    = (const float*)d_in[0];
    const float* Win  = (const float*)d_in[1];
    const float* Wres = (const float*)d_in[2];
    const float* Wout = (const float*)d_in[3];
    float* out = (float*)d_out;

    char* ws = (char*)d_ws;
    unsigned* flags = (unsigned*)ws;                 // 125 uints (4 KB reserved)
    __bf16* sG = (__bf16*)(ws + 4096);               // 2 * 8 * 2000 bf16 = 64 KB
    float* H   = (float*)(ws + 4096 + 65536);        // 2000*8*2000 f32 = 128 MB

    (void)hipMemsetAsync(d_ws, 0, 4096, stream);

    (void)hipFuncSetAttribute((const void*)esn_recur,
                              hipFuncAttributeMaxDynamicSharedMemorySize, LDS_BYTES);
    esn_recur<<<NWG, THREADS, LDS_BYTES, stream>>>(x, Win, Wres, sG, H, flags);
    esn_out<<<250, 256, 0, stream>>>(H, Wout, out);
}

// Round 5
// 7261.138 us; speedup vs baseline: 4.2347x; 1.5774x over previous
//
#include <hip/hip_runtime.h>

#define BB 8
#define TT 2000
#define DD 64
#define NN 2000
#define NWG 125
#define COLS 16
#define THREADS 512
#define SROW 2048          // bf16 elements per LDS row (4096 B, swizzled)
#define XST 68

// LDS: wS 16*2048*2=65536, sS 8*2048*2=32768, winS 16*68*4=4352, red 8*8*16*4=4096
#define LDS_BYTES (65536 + 32768 + 4352 + 4096)

typedef __bf16 bf16x8 __attribute__((ext_vector_type(8)));
typedef float f32x4 __attribute__((ext_vector_type(4)));

__device__ __forceinline__ float fast_tanh(float v) {
    float e = __expf(2.0f * v);
    return 1.0f - 2.0f / (e + 1.0f);
}

// ---- uncached (coherence-point) accessors: sc0 sc1 = bypass L1/L2, served by IC ----
__device__ __forceinline__ uint4 ld_uc4(const uint4* p) {
    uint4 v;
    asm volatile("global_load_dwordx4 %0, %1, off sc0 sc1" : "=v"(v) : "v"(p) : "memory");
    return v;
}
__device__ __forceinline__ void st_uc_u16(void* p, unsigned v) {
    asm volatile("global_store_short %0, %1, off sc0 sc1" :: "v"(p), "v"(v) : "memory");
}
__device__ __forceinline__ unsigned ld_uc_u32(const void* p) {
    unsigned v;
    asm volatile("global_load_dword %0, %1, off sc0 sc1\n\ts_waitcnt vmcnt(0)"
                 : "=v"(v) : "v"(p) : "memory");
    return v;
}

__global__ void __launch_bounds__(THREADS, 1)
esn_recur(const float* __restrict__ x, const float* __restrict__ Win,
          const float* __restrict__ Wres, __bf16* __restrict__ sG,
          float* __restrict__ H, unsigned* __restrict__ arr)
{
    extern __shared__ char smraw[];
    __bf16* wS   = (__bf16*)smraw;                 // [16][2048] swizzled: blk^(c&7)
    __bf16* sS   = wS + 16 * SROW;                 // [8][2048]  swizzled: blk^row
    float*  winS = (float*)(sS + 8 * SROW);        // [16][68]
    float*  red  = winS + 16 * XST;                // [8 waves][8 rows][16 cols]

    const int tid  = threadIdx.x;
    const int wg   = blockIdx.x;
    const int col0 = wg * COLS;
    const int wave = tid >> 6;
    const int lane = tid & 63;

    // zero all LDS (also zeroes K-pad 2000..2047 for the MFMA)
    for (int i = tid; i < LDS_BYTES / 4; i += THREADS) ((unsigned*)smraw)[i] = 0u;
    __syncthreads();

    // one-time: Wres slice transposed, bf16, XOR-swizzled 16B blocks
    {
        const int c = tid & 15, h = c & 7;
        for (int k = tid >> 4; k < NN; k += 32)
            wS[c * SROW + ((((k >> 3) ^ h) << 3) | (k & 7))] =
                (__bf16)Wres[(size_t)k * NN + col0 + c];
    }
    // one-time: Win slice (f32)
    for (int i = tid; i < COLS * DD; i += THREADS) {
        int c = i >> 6, d = i & 63;
        winS[c * XST + d] = Win[(size_t)d * NN + col0 + c];
    }
    __syncthreads();

    const int arow = lane & 7;        // A-fragment row (rows 8..15 dup 0..7)
    const int quad = lane >> 4;
    const int bcol = lane & 15;
    const int hb   = bcol & 7;
    const bool isfin = (tid < BB * COLS);   // 128 threads = waves 0,1 (wave-uniform)
    const int fb = tid >> 4, fc = tid & 15;

    for (int t = 0; t < TT; ++t) {
        // x@Win partial for THIS step — from L2-cached x, overlaps the poll wait
        float xacc = 0.f;
        if (isfin) {
            const float4* xr = (const float4*)(x + ((size_t)fb * TT + t) * DD);
            const float4* wv = (const float4*)(winS + fc * XST);
            float p0 = 0.f, p1 = 0.f, p2 = 0.f, p3 = 0.f;
            #pragma unroll
            for (int d4 = 0; d4 < 16; d4 += 4) {
                float4 x0 = xr[d4+0], x1 = xr[d4+1], x2 = xr[d4+2], x3 = xr[d4+3];
                float4 w0 = wv[d4+0], w1 = wv[d4+1], w2 = wv[d4+2], w3 = wv[d4+3];
                p0 = fmaf(x0.x,w0.x,p0); p0 = fmaf(x0.y,w0.y,p0);
                p0 = fmaf(x0.z,w0.z,p0); p0 = fmaf(x0.w,w0.w,p0);
                p1 = fmaf(x1.x,w1.x,p1); p1 = fmaf(x1.y,w1.y,p1);
                p1 = fmaf(x1.z,w1.z,p1); p1 = fmaf(x1.w,w1.w,p1);
                p2 = fmaf(x2.x,w2.x,p2); p2 = fmaf(x2.y,w2.y,p2);
                p2 = fmaf(x2.z,w2.z,p2); p2 = fmaf(x2.w,w2.w,p2);
                p3 = fmaf(x3.x,w3.x,p3); p3 = fmaf(x3.y,w3.y,p3);
                p3 = fmaf(x3.z,w3.z,p3); p3 = fmaf(x3.w,w3.w,p3);
            }
            xacc = (p0 + p1) + (p2 + p3);
        }

        if (t > 0) {
            // single-lane poll of the step's arrival counter, then release block
            if (wave == 0) {
                unsigned v = 0;
                do {
                    if (lane == 0) v = ld_uc_u32(arr + t);
                    v = __builtin_amdgcn_readfirstlane(v);
                } while (v < NWG);
            }
            __builtin_amdgcn_s_barrier();          // state_t certified at IC
            // load state row `wave` from IC (uncached), swizzled into LDS
            const uint4* srcRow =
                (const uint4*)(sG + (size_t)(t & 1) * (BB * NN) + wave * NN);
            uint4 v0 = ld_uc4(srcRow + lane);
            uint4 v1 = ld_uc4(srcRow + lane + 64);
            uint4 v2 = ld_uc4(srcRow + lane + 128);
            uint4 v3 = make_uint4(0u, 0u, 0u, 0u);
            const bool has4 = (lane < 58);         // 192+lane < 250
            if (has4) v3 = ld_uc4(srcRow + lane + 192);
            asm volatile("s_waitcnt vmcnt(0)" ::: "memory");
            __bf16* dst = sS + wave * SROW;
            *(uint4*)(dst + (size_t)((lane      ) ^ wave) * 8) = v0;
            *(uint4*)(dst + (size_t)((lane +  64) ^ wave) * 8) = v1;
            *(uint4*)(dst + (size_t)((lane + 128) ^ wave) * 8) = v2;
            if (has4) *(uint4*)(dst + (size_t)((lane + 192) ^ wave) * 8) = v3;
        }
        __syncthreads();

        // state @ Wres slice via MFMA: wave w owns K slice [w*256, (w+1)*256)
        f32x4 acc = {0.f, 0.f, 0.f, 0.f};
        if (t > 0) {
            const __bf16* aBase = sS + arow * SROW;
            const __bf16* bBase = wS + bcol * SROW;
            const int blk0 = wave * 32 + quad;
            #pragma unroll
            for (int m = 0; m < 8; ++m) {
                const int blk = blk0 + m * 4;
                bf16x8 a = *(const bf16x8*)(aBase + ((blk ^ arow) << 3));
                bf16x8 b = *(const bf16x8*)(bBase + ((blk ^ hb) << 3));
                acc = __builtin_amdgcn_mfma_f32_16x16x32_bf16(a, b, acc, 0, 0, 0);
            }
        }
        if (lane < 32) {
            const int r0 = (lane >> 4) * 4;
            #pragma unroll
            for (int i = 0; i < 4; ++i)
                red[(wave * 8 + r0 + i) * 16 + bcol] = acc[i];
        }
        __syncthreads();

        // finish: sum K-partials + precomputed x@Win, tanh, publish
        if (isfin) {
            float a2 = xacc;
            #pragma unroll
            for (int w = 0; w < 8; ++w) a2 += red[(w * 8 + fb) * 16 + fc];
            float s = fast_tanh(a2);
            if (t < TT - 1) {
                __bf16 sb = (__bf16)s;
                unsigned short us;
                __builtin_memcpy(&us, &sb, 2);
                st_uc_u16(sG + (size_t)((t + 1) & 1) * (BB * NN) + fb * NN + col0 + fc,
                          (unsigned)us);
                asm volatile("s_waitcnt vmcnt(0)" ::: "memory");  // state at IC
            }
            float hval = (fc & 1) ? s : s * s;   // even global col -> square
            H[((size_t)t * BB + fb) * NN + col0 + fc] = hval;     // in flight past barrier
        }
        if (t < TT - 1) {
            __builtin_amdgcn_s_barrier();        // all lanes' state stores at IC
            asm volatile("" ::: "memory");       // keep atomic below the barrier
            if (tid == 0) atomicAdd(arr + t + 1, 1u);
        }
    }
}

// out[b,t,:] = H[t,b,:] @ Wout  (augmentation already applied in H)
__global__ void __launch_bounds__(256, 1)
esn_out(const float* __restrict__ H, const float* __restrict__ Wout,
        float* __restrict__ out)
{
    __shared__ float Hs[64 * 84];
    __shared__ float Ws[80 * 64];
    const int tid = threadIdx.x;
    const int r0  = blockIdx.x * 64;      // global row = t*8 + b
    const int tr  = tid >> 4;             // 0..15
    const int tc  = tid & 15;             // 0..15
    float acc[4][4] = {{0.f}};

    for (int k0 = 0; k0 < NN; k0 += 80) {
        __syncthreads();
        #pragma unroll
        for (int j = 0; j < 5; ++j) {
            int idx = j * 256 + tid;               // 0..1279
            int r = idx / 20, q = idx % 20;
            *(float4*)&Hs[r * 84 + q * 4] =
                *(const float4*)&H[(size_t)(r0 + r) * NN + k0 + q * 4];
        }
        #pragma unroll
        for (int j = 0; j < 5; ++j) {
            int idx = j * 256 + tid;
            int kk = idx >> 4, c4 = idx & 15;
            *(float4*)&Ws[kk * 64 + c4 * 4] =
                *(const float4*)&Wout[(size_t)(k0 + kk) * DD + c4 * 4];
        }
        __syncthreads();
        for (int kk = 0; kk < 80; ++kk) {
            float4 wv = *(const float4*)&Ws[kk * 64 + tc * 4];
            #pragma unroll
            for (int i = 0; i < 4; ++i) {
                float hv = Hs[(tr + 16 * i) * 84 + kk];
                acc[i][0] = fmaf(hv, wv.x, acc[i][0]);
                acc[i][1] = fmaf(hv, wv.y, acc[i][1]);
                acc[i][2] = fmaf(hv, wv.z, acc[i][2]);
                acc[i][3] = fmaf(hv, wv.w, acc[i][3]);
            }
        }
    }
    #pragma unroll
    for (int i = 0; i < 4; ++i) {
        int rg = r0 + tr + 16 * i;
        int t = rg >> 3, b = rg & 7;
        *(float4*)&out[((size_t)b * TT + t) * DD + tc * 4] =
            make_float4(acc[i][0], acc[i][1], acc[i][2], acc[i][3]);
    }
}

extern "C" void kernel_launch(void* const* d_in, const int* in_sizes, int n_in,
                              void* d_out, int out_size, void* d_ws, size_t ws_size,
                              hipStream_t stream)
{
    const float* x    = (const float*)d_in[0];
    const float* Win  = (const float*)d_in[1];
    const float* Wres = (const float*)d_in[2];
    const float* Wout = (const float*)d_in[3];
    float* out = (float*)d_out;

    char* ws = (char*)d_ws;
    unsigned* arr = (unsigned*)ws;                   // 2000 dwords (8 KB reserved)
    __bf16* sG = (__bf16*)(ws + 8192);               // 2 * 8 * 2000 bf16 = 64 KB
    float* H   = (float*)(ws + 8192 + 65536);        // 2000*8*2000 f32 = 128 MB

    (void)hipMemsetAsync(d_ws, 0, 8192, stream);     // fresh arrival counters per call

    (void)hipFuncSetAttribute((const void*)esn_recur,
                              hipFuncAttributeMaxDynamicSharedMemorySize, LDS_BYTES);
    esn_recur<<<NWG, THREADS, LDS_BYTES, stream>>>(x, Win, Wres, sG, H, arr);
    esn_out<<<250, 256, 0, stream>>>(H, Wout, out);
}